// Round 9
// baseline (95.598 us; speedup 1.0000x reference)
//
#include <hip/hip_runtime.h>
#include <hip/hip_bf16.h>

#define NB 4096
#define DD 768
#define NKT 24            // K-tiles of BK=32: 768/32
#define NBLK 256          // grid: 256 blocks = 1 per CU (128KB LDS forces 1/CU) -> all co-resident

typedef __bf16 bf16x8 __attribute__((ext_vector_type(8)));
typedef float f32x4 __attribute__((ext_vector_type(4)));
typedef unsigned int uint;

#define WAITVM(N) asm volatile("s_waitcnt vmcnt(" #N ")" ::: "memory")

// ---------------- init: zero stats + grid-barrier counter (d_ws is poisoned 0xAA) ----------------
__global__ void init_kernel(float* scal)
{
    if (threadIdx.x < 16) scal[threadIdx.x] = 0.0f;
}

// ---------------- staging: one K-tile unit = A[256][32] + B[256][32] (32 KB) ----------------
// Swizzle (both sides, rule #21): logical chunk c (16B) of row r at phys chunk c ^ ((r>>1)&3).
// global_load_lds dest is linear (base+lane*16); lane's global source chunk = (lane&3)^((lane>>3)&3).
// Measured 0 bank conflicts (2-way aliasing = free, m136).
__device__ __forceinline__ void stage_tile(
    __hip_bfloat16* ldsAll,
    const __hip_bfloat16* __restrict__ vhat, const __hip_bfloat16* __restrict__ that_,
    int rowBase, int colBase, int T, int wid, int lane)
{
    int u = T & 3;
    int k0 = T * 32;
    const __hip_bfloat16* src = (wid >= 4) ? that_ : vhat;
    int tb = (wid >= 4) ? colBase : rowBase;
    int w4 = wid & 3;
    int logc = (lane & 3) ^ ((lane >> 3) & 3);
    int rowIn = w4 * 64 + (lane >> 2);
    __hip_bfloat16* dbase = ldsAll + u * 16384 + ((wid >= 4) ? 8192 : 0) + w4 * 2048;
    #pragma unroll
    for (int i = 0; i < 4; ++i) {
        const __hip_bfloat16* g = src + (size_t)(tb + rowIn + i * 16) * DD + k0 + logc * 8;
        __builtin_amdgcn_global_load_lds(
            (const __attribute__((address_space(1))) void*)g,
            (__attribute__((address_space(3))) void*)(dbase + i * 512),
            16, 0, 0);
    }
}

// ---------------- fully fused: normalize+cnt | bar1 | GEMM+stats | bar2 | exp sums | bar3 | loss ----------------
__global__ __launch_bounds__(512, 2) void fused_kernel(
    const float* __restrict__ vf, const float* __restrict__ tf, const int* __restrict__ ids,
    __hip_bfloat16* __restrict__ vhat, __hip_bfloat16* __restrict__ that_,
    float* scal, float* rs, float* cs, float* cntf, int* npart, uint* bar,
    float* __restrict__ out)
{
    __shared__ __hip_bfloat16 ldsAll[4 * 16384];   // 128 KB: ring units; reused as ids stage in phase 0
    __shared__ int idr[256], idc[256];
    __shared__ float red[24];
    __shared__ float rs_l[256], cs_l[256];
    __shared__ int bp[16], wred_i[8];
    __shared__ float ra[8], rn[8];
    __shared__ float invT_sh, mf_sh;

    int rawb = blockIdx.x;
    int t = threadIdx.x, wid = t >> 6, lane = t & 63;

    // ===== phase 0a: normalize 32 rows (1 wave = 1 row, nontemporal f32x4 loads) =====
    #pragma unroll
    for (int it = 0; it < 4; ++it) {
        int row = rawb * 32 + wid * 4 + it;
        const float* src;
        __hip_bfloat16* dst;
        if (row < NB) { src = vf + (size_t)row * DD; dst = vhat + (size_t)row * DD; }
        else          { src = tf + (size_t)(row - NB) * DD; dst = that_ + (size_t)(row - NB) * DD; }
        f32x4 x0 = __builtin_nontemporal_load((const f32x4*)(src + lane * 4));
        f32x4 x1 = __builtin_nontemporal_load((const f32x4*)(src + 256 + lane * 4));
        f32x4 x2 = __builtin_nontemporal_load((const f32x4*)(src + 512 + lane * 4));
        float s = x0[0]*x0[0] + x0[1]*x0[1] + x0[2]*x0[2] + x0[3]*x0[3]
                + x1[0]*x1[0] + x1[1]*x1[1] + x1[2]*x1[2] + x1[3]*x1[3]
                + x2[0]*x2[0] + x2[1]*x2[1] + x2[2]*x2[2] + x2[3]*x2[3];
        #pragma unroll
        for (int off = 1; off < 64; off <<= 1) s += __shfl_xor(s, off, 64);
        float scale = 1.0f / sqrtf(s);
        unsigned short* dsh = (unsigned short*)dst;
        ushort4 o0, o1, o2;
        o0.x = __builtin_bit_cast(unsigned short, __float2bfloat16(x0[0] * scale));
        o0.y = __builtin_bit_cast(unsigned short, __float2bfloat16(x0[1] * scale));
        o0.z = __builtin_bit_cast(unsigned short, __float2bfloat16(x0[2] * scale));
        o0.w = __builtin_bit_cast(unsigned short, __float2bfloat16(x0[3] * scale));
        o1.x = __builtin_bit_cast(unsigned short, __float2bfloat16(x1[0] * scale));
        o1.y = __builtin_bit_cast(unsigned short, __float2bfloat16(x1[1] * scale));
        o1.z = __builtin_bit_cast(unsigned short, __float2bfloat16(x1[2] * scale));
        o1.w = __builtin_bit_cast(unsigned short, __float2bfloat16(x1[3] * scale));
        o2.x = __builtin_bit_cast(unsigned short, __float2bfloat16(x2[0] * scale));
        o2.y = __builtin_bit_cast(unsigned short, __float2bfloat16(x2[1] * scale));
        o2.z = __builtin_bit_cast(unsigned short, __float2bfloat16(x2[2] * scale));
        o2.w = __builtin_bit_cast(unsigned short, __float2bfloat16(x2[3] * scale));
        *(ushort4*)(dsh + lane * 4)       = o0;
        *(ushort4*)(dsh + 256 + lane * 4) = o1;
        *(ushort4*)(dsh + 512 + lane * 4) = o2;
    }

    // ===== phase 0b: cnt — ids staged into ldsAll; 32 lanes per id, int4 scan =====
    int* idsh = (int*)ldsAll;
    for (int i = t; i < NB; i += 512) idsh[i] = ids[i];
    __syncthreads();
    {
        int sub = t >> 5, l32 = t & 31;
        int my = idsh[rawb * 16 + sub];
        const int4* idsh4 = (const int4*)idsh;
        int c = 0;
        #pragma unroll 8
        for (int j = l32; j < NB / 4; j += 32) {
            int4 v = idsh4[j];
            c += (v.x == my) + (v.y == my) + (v.z == my) + (v.w == my);
        }
        #pragma unroll
        for (int off = 16; off > 0; off >>= 1) c += __shfl_down(c, off, 32);
        if (l32 == 0) { cntf[rawb * 16 + sub] = (float)c; bp[sub] = c; }
    }
    // ===== phase 0c: zero rs+cs (contiguous 8192 floats starting at rs) =====
    if (t < 32) rs[rawb * 32 + t] = 0.0f;
    __syncthreads();
    if (t == 0) {
        int s = 0;
        #pragma unroll
        for (int i = 0; i < 16; ++i) s += bp[i];
        npart[rawb] = s;
    }

    // ===== grid barrier #1: vhat/that/cntf/npart/rs-zero published =====
    __syncthreads();
    if (t == 0) {
        __hip_atomic_fetch_add(bar, 1u, __ATOMIC_ACQ_REL, __HIP_MEMORY_SCOPE_AGENT);
        while (__hip_atomic_load(bar, __ATOMIC_ACQUIRE, __HIP_MEMORY_SCOPE_AGENT) < NBLK)
            __builtin_amdgcn_s_sleep(2);
    }
    __syncthreads();

    // ===== GEMM: 256x256 tile, 8 waves, BK=32, 4-deep ring, ONE barrier per tile =====
    // XCD-chunked bijective swizzle: 8 regions of 4by x 8bx (grid 256 = 16x16)
    int rg = rawb & 7, sq = rawb >> 3;
    int by = (rg >> 1) * 4 + (sq >> 3);
    int bx = (rg & 1) * 8 + (sq & 7);
    int rowBase = by * 256, colBase = bx * 256;
    int wr = wid >> 2, wc = wid & 3;
    int fr = lane & 15, g = lane >> 4;

    f32x4 acc[8][4];
    #pragma unroll
    for (int m = 0; m < 8; ++m)
        #pragma unroll
        for (int n = 0; n < 4; ++n) acc[m][n] = (f32x4){0.f, 0.f, 0.f, 0.f};

    int pcoff = ((g ^ ((fr >> 1) & 3)) * 8);
    int aoff = (wr * 128 + fr) * 32 + pcoff;
    int boff = 8192 + (wc * 64 + fr) * 32 + pcoff;

    stage_tile(ldsAll, vhat, that_, rowBase, colBase, 0, wid, lane);
    stage_tile(ldsAll, vhat, that_, rowBase, colBase, 1, wid, lane);
    stage_tile(ldsAll, vhat, that_, rowBase, colBase, 2, wid, lane);
    WAITVM(8);
    __builtin_amdgcn_s_barrier();

    // Hazard ledger: iter T stages T+3 into unit (T+3)&3=(T-1)&3 — all waves finished
    // reading T-1 before the barrier ending iter T-1 (every ds_read feeds an MFMA, so
    // reads retire before the wave's last MFMA issues). Reads of tile T are safe: the
    // WAITVM(8) at end of iter T-1 retires exactly tile T's 4 staging loads.
    for (int T = 0; T < NKT; ++T) {
        const __hip_bfloat16* U = ldsAll + (T & 3) * 16384;
        if (T + 3 < NKT)
            stage_tile(ldsAll, vhat, that_, rowBase, colBase, T + 3, wid, lane);
        bf16x8 a0[4], bb[4], a1[4];
        #pragma unroll
        for (int m = 0; m < 4; ++m) a0[m] = *(const bf16x8*)(U + aoff + m * 512);
        #pragma unroll
        for (int n = 0; n < 4; ++n) bb[n] = *(const bf16x8*)(U + boff + n * 512);
        #pragma unroll
        for (int m = 0; m < 4; ++m) a1[m] = *(const bf16x8*)(U + aoff + (m + 4) * 512);
        __builtin_amdgcn_s_setprio(1);
        #pragma unroll
        for (int m = 0; m < 4; ++m)
            #pragma unroll
            for (int n = 0; n < 4; ++n)
                acc[m][n] = __builtin_amdgcn_mfma_f32_16x16x32_bf16(a0[m], bb[n], acc[m][n], 0, 0, 0);
        #pragma unroll
        for (int m = 0; m < 4; ++m)
            #pragma unroll
            for (int n = 0; n < 4; ++n)
                acc[m + 4][n] = __builtin_amdgcn_mfma_f32_16x16x32_bf16(a1[m], bb[n], acc[m + 4][n], 0, 0, 0);
        __builtin_amdgcn_s_setprio(0);
        // tile boundary: T+1 staged; keep T+2/T+3 in flight (never vmcnt 0 mid-loop)
        if (T < NKT - 3)       { WAITVM(8); }
        else if (T == NKT - 3) { WAITVM(4); }
        else if (T == NKT - 2) { WAITVM(0); }
        __builtin_amdgcn_s_barrier();
    }

    // ===== stats: {total, S_mf, trace};  C/D: col=fr, row=g*4+reg [m89-verified] =====
    if (t < 256) idr[t] = ids[rowBase + t];
    else         idc[t - 256] = ids[colBase + (t - 256)];
    __syncthreads();
    {
        float tsum = 0.f, msum = 0.f, dsum = 0.f;
        #pragma unroll
        for (int m = 0; m < 8; ++m) {
            int rl = wr * 128 + m * 16 + g * 4;
            #pragma unroll
            for (int n = 0; n < 4; ++n) {
                int cl = wc * 64 + n * 16 + fr;
                int colId = idc[cl];
                int gj = colBase + cl;
                #pragma unroll
                for (int r = 0; r < 4; ++r) {
                    float val = acc[m][n][r];
                    tsum += val;
                    if (idr[rl + r] == colId) msum += val;
                    if (rowBase + rl + r == gj) dsum += val;
                }
            }
        }
        #pragma unroll
        for (int off = 32; off > 0; off >>= 1) {
            tsum += __shfl_down(tsum, off, 64);
            msum += __shfl_down(msum, off, 64);
            dsum += __shfl_down(dsum, off, 64);
        }
        if (lane == 0) { red[wid] = tsum; red[8 + wid] = msum; red[16 + wid] = dsum; }
        __syncthreads();
        if (t == 0) {
            float s0 = 0.f, s1 = 0.f, s2 = 0.f;
            #pragma unroll
            for (int w = 0; w < 8; ++w) { s0 += red[w]; s1 += red[8 + w]; s2 += red[16 + w]; }
            atomicAdd(&scal[0], s0);
            atomicAdd(&scal[1], s1);
            atomicAdd(&scal[2], s2);
        }
    }

    // ===== grid barrier #2: stats complete =====
    __syncthreads();
    if (t == 0) {
        __hip_atomic_fetch_add(bar, 1u, __ATOMIC_ACQ_REL, __HIP_MEMORY_SCOPE_AGENT);
        while (__hip_atomic_load(bar, __ATOMIC_ACQUIRE, __HIP_MEMORY_SCOPE_AGENT) < 2 * NBLK)
            __builtin_amdgcn_s_sleep(2);
    }
    __syncthreads();

    // ===== np reduce + invT (all blocks need it) =====
    {
        int myn = (t < NBLK) ? npart[t] : 0;
        #pragma unroll
        for (int off = 32; off > 0; off >>= 1) myn += __shfl_down(myn, off, 64);
        if (lane == 0) wred_i[wid] = myn;
        __syncthreads();
        if (t == 0) {
            int npi = 0;
            #pragma unroll
            for (int w = 0; w < 8; ++w) npi += wred_i[w];
            float total = __hip_atomic_load(&scal[0], __ATOMIC_RELAXED, __HIP_MEMORY_SCOPE_AGENT);
            float mf    = __hip_atomic_load(&scal[1], __ATOMIC_RELAXED, __HIP_MEMORY_SCOPE_AGENT);
            float trace = __hip_atomic_load(&scal[2], __ATOMIC_RELAXED, __HIP_MEMORY_SCOPE_AGENT);
            float np = (float)npi;
            float pos_cnt = np - (float)NB;
            float neg_cnt = (float)NB * (float)NB - np;
            float pos_mean = (mf - trace) / fmaxf(1.0f, pos_cnt);
            float neg_mean = (total - mf) / fmaxf(1.0f, neg_cnt);
            float sep = pos_mean - neg_mean;
            float temp = 0.07f * (0.8f + 0.4f * expf(-2.0f * sep));
            temp = fminf(fmaxf(temp, 0.04f), 0.2f);
            invT_sh = 1.0f / temp;
            mf_sh = mf;
        }
        if (t < 256) { rs_l[t] = 0.0f; cs_l[t] = 0.0f; }
        __syncthreads();
    }
    float invT = invT_sh;

    // ===== exp((sim-1)/temp) row & col sums straight from registers =====
    #pragma unroll
    for (int m = 0; m < 8; ++m)
        #pragma unroll
        for (int n = 0; n < 4; ++n)
            #pragma unroll
            for (int r = 0; r < 4; ++r)
                acc[m][n][r] = __expf((acc[m][n][r] - 1.0f) * invT);
    #pragma unroll
    for (int m = 0; m < 8; ++m) {
        #pragma unroll
        for (int r = 0; r < 4; ++r) {
            float rp = 0.f;
            #pragma unroll
            for (int n = 0; n < 4; ++n) rp += acc[m][n][r];
            rp += __shfl_xor(rp, 1, 64);
            rp += __shfl_xor(rp, 2, 64);
            rp += __shfl_xor(rp, 4, 64);
            rp += __shfl_xor(rp, 8, 64);
            if (fr == 0) atomicAdd(&rs_l[wr * 128 + m * 16 + g * 4 + r], rp);
        }
    }
    #pragma unroll
    for (int n = 0; n < 4; ++n) {
        float cp = 0.f;
        #pragma unroll
        for (int m = 0; m < 8; ++m)
            #pragma unroll
            for (int r = 0; r < 4; ++r) cp += acc[m][n][r];
        cp += __shfl_xor(cp, 16, 64);
        cp += __shfl_xor(cp, 32, 64);
        if (g == 0) atomicAdd(&cs_l[wc * 64 + n * 16 + fr], cp);
    }
    __syncthreads();
    if (t < 256) {
        atomicAdd(&rs[rowBase + t], rs_l[t]);
        atomicAdd(&cs[colBase + t], cs_l[t]);
    }

    // ===== barrier #3: all arrive; only block 0 spins and finishes =====
    __syncthreads();
    if (t == 0)
        __hip_atomic_fetch_add(bar, 1u, __ATOMIC_ACQ_REL, __HIP_MEMORY_SCOPE_AGENT);
    if (rawb != 0) return;
    if (t == 0) {
        while (__hip_atomic_load(bar, __ATOMIC_ACQUIRE, __HIP_MEMORY_SCOPE_AGENT) < 3 * NBLK)
            __builtin_amdgcn_s_sleep(2);
    }
    __syncthreads();

    // ===== final loss (block 0, 512 threads) =====
    {
        float a = 0.f, npl = 0.f;
        for (int i = t; i < NB; i += 512) {
            float cf = cntf[i];
            a += cf * (logf(rs[i]) + logf(cs[i]));
            npl += cf;
        }
        #pragma unroll
        for (int off = 32; off > 0; off >>= 1) {
            a += __shfl_down(a, off, 64);
            npl += __shfl_down(npl, off, 64);
        }
        if (lane == 0) { ra[wid] = a; rn[wid] = npl; }
        __syncthreads();
        if (t == 0) {
            float A = 0.f, np = 0.f;
            #pragma unroll
            for (int w = 0; w < 8; ++w) { A += ra[w]; np += rn[w]; }
            // lse_row[i] = 1/temp + log(rs[i]); v2t+t2v = sum cnt*(lse_r+lse_c) - 2*mf/temp
            out[0] = (A + 2.0f * invT_sh * (np - mf_sh)) / (2.0f * np);
        }
    }
}

extern "C" void kernel_launch(void* const* d_in, const int* in_sizes, int n_in,
                              void* d_out, int out_size, void* d_ws, size_t ws_size,
                              hipStream_t stream)
{
    const float* vf  = (const float*)d_in[0];
    const float* tf  = (const float*)d_in[1];
    const int*   ids = (const int*)d_in[2];

    float* ws_f = (float*)d_ws;
    float* scal = ws_f;                 // [0]=total [1]=S_mf [2]=trace [6]=bar
    float* rs   = ws_f + 16;            // 4096  (cs contiguous after rs — fused zeroes both via rs)
    float* cs   = ws_f + 16 + 4096;     // 4096
    float* cntf = ws_f + 16 + 8192;     // 4096
    int* npart  = (int*)(ws_f + 16 + 12288);   // 256 partial num_pos counts
    uint* bar   = (uint*)(scal + 6);
    __hip_bfloat16* vhat  = (__hip_bfloat16*)((char*)d_ws + 131072);
    __hip_bfloat16* that_ = vhat + (size_t)NB * DD;

    init_kernel<<<1, 64, 0, stream>>>(scal);
    fused_kernel<<<NBLK, 512, 0, stream>>>(vf, tf, ids, vhat, that_,
                                           scal, rs, cs, cntf, npart, bar, (float*)d_out);
}